// Round 21
// baseline (419.570 us; speedup 1.0000x reference)
//
#include <hip/hip_runtime.h>
#include <math.h>

#define D    6
#define S    128
#define H    128
#define WIN  16
#define BB   8
#define TT   513
#define NW   32
#define OUTD 10

// ---- device-global scratch ----
__device__ float g_lvl1[BB * NW * D];
__device__ float g_area[BB * NW * D * D];
__device__ float g_h0[BB * S];
__device__ float g_hist[BB * (NW + 1) * S];
__device__ float4 g_W2p[3 * 16 * 512];    // packed W2 for S3: [ptr][quad i][tid]
__device__ float4 g_W2p6[64 * 384];       // packed W2 for S6: [i][thread]

__device__ __forceinline__ float sp(float x) {
    return (x > 20.f) ? x : log1pf(expf(x));
}
__device__ __forceinline__ float sigm(float x) {
    return 1.f / (1.f + expf(-x));
}
__device__ __forceinline__ float dot4(float4 a, float4 b, float acc) {
    return fmaf(a.x, b.x, fmaf(a.y, b.y, fmaf(a.z, b.z, fmaf(a.w, b.w, acc))));
}

// ---- LDS layout (float offsets) ----
#define O_W0   0        // [128 r][128 k] fp32 row-major
#define O_W1   16384
#define O_PS   32768    // psum [4 c][6 i][128 r] (3072); aliased psumV [2][768] / [768]
#define O_U    35840    // [6][128] T2
#define O_T    36608    // [6][128] T1
#define O_V    37376    // [768]
#define O_H    38144    // [128] h single buffer
#define O_U1   38400
#define O_U2   38528
#define O_SG1  38656
#define O_SG2  38784
#define O_B0   38912
#define O_B1   39040
#define O_SIG  39168    // [2][44]
#define O_B2   39256    // [768] bv2 staged
#define SMTOT  40024    // 160,096 B

// ---- K0a: pack W2 for S3 (kh-half row triples) ----
__global__ __launch_bounds__(512) void k_pack(const float* __restrict__ Wv2) {
    const float4* W24 = (const float4*)Wv2;          // [768][32]
    int e = blockIdx.x * 512 + threadIdx.x;
    if (e < 3 * 16 * 512) {
        int ptr = e >> 13;
        int rem = e & 8191;
        int i   = rem >> 9;
        int tid = rem & 511;
        int r0 = tid >> 1, kh = tid & 1;
        int row = r0 + ptr * 256;
        g_W2p[e] = W24[row * 32 + kh * 16 + i];
    }
}

// ---- K0b: pack W2 for S6 (same-j-block row pairs, full k) ----
__global__ __launch_bounds__(512) void k_pack6(const float* __restrict__ Wv2) {
    const float4* W24 = (const float4*)Wv2;          // [768][32]
    int e = blockIdx.x * 512 + threadIdx.x;
    if (e < 64 * 384) {
        int i = e / 384;
        int t = e % 384;
        int jb = t >> 6, pr = t & 63;
        int row = jb * 128 + 2 * pr + (i >> 5);      // i<32 -> row0, else row1
        g_W2p6[e] = W24[row * 32 + (i & 31)];
    }
}

// ---- K2: windowed log-signature + init MLP ----
__global__ __launch_bounds__(256) void k_sig(
        const float* __restrict__ x,
        const float* __restrict__ Wi0, const float* __restrict__ bi0,
        const float* __restrict__ Wi1, const float* __restrict__ bi1,
        const float* __restrict__ Wi2, const float* __restrict__ bi2) {
    const int b = blockIdx.x;
    const int tid = threadIdx.x;
    __shared__ float dxs[NW][WIN][D];
    __shared__ float cums[NW][WIN][D];
    __shared__ float ua[H], ub[H];

    const float* xb = x + (size_t)b * TT * D;

    if (tid < NW * D) {
        int w = tid / D, i = tid % D;
        float run = 0.f;
        float prev = xb[(w * WIN) * D + i];
        for (int k = 0; k < WIN; ++k) {
            float cur = xb[(w * WIN + k + 1) * D + i];
            float d = cur - prev; prev = cur;
            dxs[w][k][i] = d;
            cums[w][k][i] = run;
            run += d;
        }
        g_lvl1[(b * NW + w) * D + i] = run;
    }
    __syncthreads();
    for (int e = tid; e < NW * D * D; e += blockDim.x) {
        int w = e / (D * D); int rem = e % (D * D);
        int i = rem / D, j = rem % D;
        float s = 0.f;
        for (int k = 0; k < WIN; ++k)
            s += cums[w][k][i] * dxs[w][k][j] - cums[w][k][j] * dxs[w][k][i];
        g_area[(b * NW + w) * (D * D) + rem] = 0.5f * s;
    }
    if (tid < H) {
        float z = bi0[tid];
        for (int k = 0; k < D; ++k) z += Wi0[tid * D + k] * xb[k];
        ua[tid] = sp(z);
    }
    __syncthreads();
    if (tid < H) {
        float z = bi1[tid];
        for (int k = 0; k < H; ++k) z += Wi1[tid * H + k] * ua[k];
        ub[tid] = sp(z);
    }
    __syncthreads();
    if (tid < H) {
        float z = bi2[tid];
        for (int k = 0; k < H; ++k) z += Wi2[tid * H + k] * ub[k];
        g_h0[b * S + tid] = z;
    }
}

// ---- K3: 8 blocks x 512 threads; LDS-instruction-minimized phases ----
__global__ __launch_bounds__(512, 2) void k_scan(
        const float* __restrict__ bv0, const float* __restrict__ bv1,
        const float* __restrict__ bv2,
        const float* __restrict__ Wv0, const float* __restrict__ Wv1) {
    __shared__ float sm[SMTOT];
    const int tid = threadIdx.x;
    const int b = blockIdx.x;
    // S1/S2 roles
    const int r   = tid & 127;
    const int c4  = tid >> 7;
    const int key = r & 7;
    // S3 roles (kh row triples)
    const int kh = tid & 1;
    const int r0 = tid >> 1, r1 = r0 + 256, r2 = r0 + 512;
    // S4/S5 roles (2-row pairs, 256 threads)
    const int c4b = tid >> 6;        // 0..3 for tid<256 (wave-uniform)
    const int rp  = tid & 63;
    const int keyb = rp & 7;
    // S6 roles (same-jb row pairs, 384 threads)
    const int jb = tid >> 6;         // 0..5 for tid<384 (wave-uniform)
    const int pr = tid & 63;

    // stage W0, W1, biases
    {
        float4* d = (float4*)(sm + O_W0);
        const float4* s0 = (const float4*)Wv0;
        const float4* s1 = (const float4*)Wv1;
        for (int i = tid; i < 4096; i += 512) { d[i] = s0[i]; d[4096 + i] = s1[i]; }
        sm[O_B2 + tid] = bv2[tid];
        if (tid < 256) sm[O_B2 + 512 + tid] = bv2[512 + tid];
        if (tid < 128) { sm[O_B0 + tid] = bv0[tid]; sm[O_B1 + tid] = bv1[tid]; }
    }
    const float4* WAp = g_W2p + tid;
    const float4* WBp = g_W2p + 8192 + tid;
    const float4* WCp = g_W2p + 16384 + tid;
    if (tid < 128) {
        float h0v = g_h0[b * 128 + tid];
        sm[O_H + tid] = h0v;
        g_hist[(b * (NW + 1)) * 128 + tid] = h0v;
    }
    if (tid >= 448) {
        int q = tid - 448;
        if (q < 42)
            sm[O_SIG + q] = (q < 6) ? g_lvl1[(b * NW) * 6 + q]
                                    : g_area[(b * NW) * 36 + q - 6];
    }
    __syncthreads();

    const float4* W04 = (const float4*)(sm + O_W0);
    const float4* W14 = (const float4*)(sm + O_W1);

    for (int t = 0; t < NW; ++t) {
        float rsig = 0.f;
        if (tid >= 448) {
            int q = tid - 448;
            if (q < 42 && t + 1 < NW)
                rsig = (q < 6) ? g_lvl1[(b * NW + t + 1) * 6 + q]
                               : g_area[(b * NW + t + 1) * 36 + q - 6];
        }
        const int sb = O_SIG + (t & 1) * 44;

        // ---- S1: psum = W0 . h ----
        {
            float a = 0.f;
            const float4* H4 = (const float4*)(sm + O_H);
            #pragma unroll
            for (int q = 0; q < 8; ++q) {
                int qq = c4 * 8 + (q ^ key);
                a = dot4(W04[r * 32 + qq], H4[qq], a);
            }
            sm[O_PS + (c4 * 6) * 128 + r] = a;
        }
        __syncthreads();
        // ---- R1 ----
        if (tid < 128) {
            float z = sm[O_B0 + tid];
            #pragma unroll
            for (int c = 0; c < 4; ++c) z += sm[O_PS + (c * 6) * 128 + tid];
            sm[O_U1 + tid] = sp(z); sm[O_SG1 + tid] = sigm(z);
        }
        __syncthreads();
        // ---- S2: psum = W1 . u1 ----
        {
            float a = 0.f;
            const float4* U14 = (const float4*)(sm + O_U1);
            #pragma unroll
            for (int q = 0; q < 8; ++q) {
                int qq = c4 * 8 + (q ^ key);
                a = dot4(W14[r * 32 + qq], U14[qq], a);
            }
            sm[O_PS + (c4 * 6) * 128 + r] = a;
        }
        __syncthreads();
        // ---- R2 ----
        if (tid < 128) {
            float z = sm[O_B1 + tid];
            #pragma unroll
            for (int c = 0; c < 4; ++c) z += sm[O_PS + (c * 6) * 128 + tid];
            sm[O_U2 + tid] = sp(z); sm[O_SG2 + tid] = sigm(z);
        }
        __syncthreads();
        // ---- S3: psumV = W2 . u2 (packed coalesced stream, kh halves) ----
        {
            float acc0 = 0.f, acc1 = 0.f, acc2 = 0.f;
            const float4* U24 = (const float4*)(sm + O_U2) + kh * 16;
            #pragma unroll 4
            for (int i = 0; i < 16; ++i) {
                float4 u = U24[i];
                acc0 = dot4(WAp[i * 512], u, acc0);
                acc1 = dot4(WBp[i * 512], u, acc1);
                acc2 = dot4(WCp[i * 512], u, acc2);
            }
            sm[O_PS + kh * 768 + r0] = acc0;
            sm[O_PS + kh * 768 + r1] = acc1;
            sm[O_PS + kh * 768 + r2] = acc2;
        }
        __syncthreads();
        // ---- R3: V = tanh(b2 + psV0 + psV1) ----
        {
            sm[O_V + tid] = tanhf(sm[O_B2 + tid] + sm[O_PS + tid] + sm[O_PS + 768 + tid]);
            if (tid < 256) {
                int e = tid + 512;
                sm[O_V + e] = tanhf(sm[O_B2 + e] + sm[O_PS + e] + sm[O_PS + 768 + e]);
            }
        }
        __syncthreads();
        // ---- S4: psum[c][i][2rp..] = W0[row-pair] . V_i (act reads shared x2 rows) ----
        if (tid < 256) {
            float aa0=0,aa1=0,aa2=0,aa3=0,aa4=0,aa5=0;
            float bb0=0,bb1=0,bb2=0,bb3=0,bb4=0,bb5=0;
            const float4* V4 = (const float4*)(sm + O_V);
            #pragma unroll
            for (int q = 0; q < 8; ++q) {
                int qq = c4b * 8 + (q ^ keyb);
                float4 we = W04[(2 * rp) * 32 + qq];
                float4 wo = W04[(2 * rp + 1) * 32 + qq];
                float4 v0 = V4[qq];
                float4 v1 = V4[32 + qq];
                float4 v2 = V4[64 + qq];
                float4 v3 = V4[96 + qq];
                float4 v4 = V4[128 + qq];
                float4 v5 = V4[160 + qq];
                aa0 = dot4(we, v0, aa0); bb0 = dot4(wo, v0, bb0);
                aa1 = dot4(we, v1, aa1); bb1 = dot4(wo, v1, bb1);
                aa2 = dot4(we, v2, aa2); bb2 = dot4(wo, v2, bb2);
                aa3 = dot4(we, v3, aa3); bb3 = dot4(wo, v3, bb3);
                aa4 = dot4(we, v4, aa4); bb4 = dot4(wo, v4, bb4);
                aa5 = dot4(we, v5, aa5); bb5 = dot4(wo, v5, bb5);
            }
            *(float2*)&sm[O_PS + (c4b * 6 + 0) * 128 + 2 * rp] = make_float2(aa0, bb0);
            *(float2*)&sm[O_PS + (c4b * 6 + 1) * 128 + 2 * rp] = make_float2(aa1, bb1);
            *(float2*)&sm[O_PS + (c4b * 6 + 2) * 128 + 2 * rp] = make_float2(aa2, bb2);
            *(float2*)&sm[O_PS + (c4b * 6 + 3) * 128 + 2 * rp] = make_float2(aa3, bb3);
            *(float2*)&sm[O_PS + (c4b * 6 + 4) * 128 + 2 * rp] = make_float2(aa4, bb4);
            *(float2*)&sm[O_PS + (c4b * 6 + 5) * 128 + 2 * rp] = make_float2(aa5, bb5);
        }
        __syncthreads();
        // ---- R4': per-row y sums once, area fold, T1 (128 threads) ----
        if (tid < 128) {
            float y0 = sm[O_PS + 0 * 128 + tid] + sm[O_PS + 6 * 128 + tid]
                     + sm[O_PS + 12 * 128 + tid] + sm[O_PS + 18 * 128 + tid];
            float y1 = sm[O_PS + 1 * 128 + tid] + sm[O_PS + 7 * 128 + tid]
                     + sm[O_PS + 13 * 128 + tid] + sm[O_PS + 19 * 128 + tid];
            float y2 = sm[O_PS + 2 * 128 + tid] + sm[O_PS + 8 * 128 + tid]
                     + sm[O_PS + 14 * 128 + tid] + sm[O_PS + 20 * 128 + tid];
            float y3 = sm[O_PS + 3 * 128 + tid] + sm[O_PS + 9 * 128 + tid]
                     + sm[O_PS + 15 * 128 + tid] + sm[O_PS + 21 * 128 + tid];
            float y4 = sm[O_PS + 4 * 128 + tid] + sm[O_PS + 10 * 128 + tid]
                     + sm[O_PS + 16 * 128 + tid] + sm[O_PS + 22 * 128 + tid];
            float y5 = sm[O_PS + 5 * 128 + tid] + sm[O_PS + 11 * 128 + tid]
                     + sm[O_PS + 17 * 128 + tid] + sm[O_PS + 23 * 128 + tid];
            float sg = sm[O_SG1 + tid];
            const float* A0 = sm + sb + 6;
            #pragma unroll
            for (int j = 0; j < 6; ++j) {
                float sv = A0[0 * 6 + j] * y0 + A0[1 * 6 + j] * y1
                         + A0[2 * 6 + j] * y2 + A0[3 * 6 + j] * y3
                         + A0[4 * 6 + j] * y4 + A0[5 * 6 + j] * y5;
                sm[O_T + j * 128 + tid] = sg * sv;
            }
        }
        __syncthreads();
        // ---- S5: psum[c][j][2rp..] = W1[row-pair] . T1_j ----
        if (tid < 256) {
            float aa0=0,aa1=0,aa2=0,aa3=0,aa4=0,aa5=0;
            float bb0=0,bb1=0,bb2=0,bb3=0,bb4=0,bb5=0;
            const float4* T4 = (const float4*)(sm + O_T);
            #pragma unroll
            for (int q = 0; q < 8; ++q) {
                int qq = c4b * 8 + (q ^ keyb);
                float4 we = W14[(2 * rp) * 32 + qq];
                float4 wo = W14[(2 * rp + 1) * 32 + qq];
                float4 v0 = T4[qq];
                float4 v1 = T4[32 + qq];
                float4 v2 = T4[64 + qq];
                float4 v3 = T4[96 + qq];
                float4 v4 = T4[128 + qq];
                float4 v5 = T4[160 + qq];
                aa0 = dot4(we, v0, aa0); bb0 = dot4(wo, v0, bb0);
                aa1 = dot4(we, v1, aa1); bb1 = dot4(wo, v1, bb1);
                aa2 = dot4(we, v2, aa2); bb2 = dot4(wo, v2, bb2);
                aa3 = dot4(we, v3, aa3); bb3 = dot4(wo, v3, bb3);
                aa4 = dot4(we, v4, aa4); bb4 = dot4(wo, v4, bb4);
                aa5 = dot4(we, v5, aa5); bb5 = dot4(wo, v5, bb5);
            }
            *(float2*)&sm[O_PS + (c4b * 6 + 0) * 128 + 2 * rp] = make_float2(aa0, bb0);
            *(float2*)&sm[O_PS + (c4b * 6 + 1) * 128 + 2 * rp] = make_float2(aa1, bb1);
            *(float2*)&sm[O_PS + (c4b * 6 + 2) * 128 + 2 * rp] = make_float2(aa2, bb2);
            *(float2*)&sm[O_PS + (c4b * 6 + 3) * 128 + 2 * rp] = make_float2(aa3, bb3);
            *(float2*)&sm[O_PS + (c4b * 6 + 4) * 128 + 2 * rp] = make_float2(aa4, bb4);
            *(float2*)&sm[O_PS + (c4b * 6 + 5) * 128 + 2 * rp] = make_float2(aa5, bb5);
        }
        __syncthreads();
        // ---- R5: T2_j = sg2 .* sum_c (128 threads) ----
        if (tid < 128) {
            float sg = sm[O_SG2 + tid];
            #pragma unroll
            for (int j = 0; j < 6; ++j) {
                float sv = sm[O_PS + j * 128 + tid] + sm[O_PS + (6 + j) * 128 + tid]
                         + sm[O_PS + (12 + j) * 128 + tid] + sm[O_PS + (18 + j) * 128 + tid];
                sm[O_U + j * 128 + tid] = sg * sv;
            }
        }
        __syncthreads();
        // ---- S6: psumV[row] = W2row . T2_jb (same-jb pairs, full-k, coalesced) ----
        if (tid < 384) {
            float acc0 = 0.f, acc1 = 0.f;
            const float4* T6 = (const float4*)(sm + O_U) + jb * 32;
            const float4* W6a = g_W2p6 + tid;            // row 2pr   of block jb
            const float4* W6b = g_W2p6 + 32 * 384 + tid; // row 2pr+1 of block jb
            #pragma unroll 4
            for (int i = 0; i < 32; ++i) {
                float4 tv = T6[i];
                acc0 = dot4(W6a[i * 384], tv, acc0);
                acc1 = dot4(W6b[i * 384], tv, acc1);
            }
            *(float2*)&sm[O_PS + jb * 128 + 2 * pr] = make_float2(acc0, acc1);
        }
        __syncthreads();
        // ---- H: h += l1.V + sum_j (1-V^2)*psV_j; hist; sig store ----
        if (tid < 128) {
            float xh = sm[O_H + tid];
            #pragma unroll
            for (int i = 0; i < 6; ++i)
                xh = fmaf(sm[sb + i], sm[O_V + i * 128 + tid], xh);
            #pragma unroll
            for (int j = 0; j < 6; ++j) {
                float v = sm[O_V + j * 128 + tid];
                xh += (1.f - v * v) * sm[O_PS + j * 128 + tid];
            }
            sm[O_H + tid] = xh;
            g_hist[(b * (NW + 1) + t + 1) * 128 + tid] = xh;
        }
        if (tid >= 448) {
            int q = tid - 448;
            if (q < 42 && t + 1 < NW)
                sm[O_SIG + ((t + 1) & 1) * 44 + q] = rsig;
        }
        __syncthreads();
    }
}

// ---- K4: readout ----
__global__ __launch_bounds__(384) void k_read(const float* __restrict__ Wr,
                                              const float* __restrict__ br,
                                              float* __restrict__ out) {
    const int b = blockIdx.x, e = threadIdx.x;
    if (e < (NW + 1) * OUTD) {
        int t = e / OUTD, o = e % OUTD;
        float z = br[o];
        const float4* hrow = (const float4*)&g_hist[(b * (NW + 1) + t) * 128];
        const float4* wrow = (const float4*)&Wr[o * 128];
        float z0 = 0, z1 = 0, z2 = 0, z3 = 0;
        #pragma unroll 8
        for (int s4 = 0; s4 < 32; ++s4) {
            float4 hv = hrow[s4]; float4 wv = wrow[s4];
            z0 = fmaf(hv.x, wv.x, z0); z1 = fmaf(hv.y, wv.y, z1);
            z2 = fmaf(hv.z, wv.z, z2); z3 = fmaf(hv.w, wv.w, z3);
        }
        out[(b * (NW + 1) + t) * OUTD + o] = z + ((z0 + z1) + (z2 + z3));
    }
}

extern "C" void kernel_launch(void* const* d_in, const int* in_sizes, int n_in,
                              void* d_out, int out_size, void* d_ws, size_t ws_size,
                              hipStream_t stream) {
    const float* x   = (const float*)d_in[0];
    const float* Wi0 = (const float*)d_in[1];
    const float* bi0 = (const float*)d_in[2];
    const float* Wi1 = (const float*)d_in[3];
    const float* bi1 = (const float*)d_in[4];
    const float* Wi2 = (const float*)d_in[5];
    const float* bi2 = (const float*)d_in[6];
    const float* Wv0 = (const float*)d_in[7];
    const float* bv0 = (const float*)d_in[8];
    const float* Wv1 = (const float*)d_in[9];
    const float* bv1 = (const float*)d_in[10];
    const float* Wv2 = (const float*)d_in[11];
    const float* bv2 = (const float*)d_in[12];
    const float* Wr  = (const float*)d_in[13];
    const float* br  = (const float*)d_in[14];
    float* out = (float*)d_out;

    hipLaunchKernelGGL(k_pack,  dim3(48), dim3(512), 0, stream, Wv2);
    hipLaunchKernelGGL(k_pack6, dim3(48), dim3(512), 0, stream, Wv2);
    hipLaunchKernelGGL(k_sig,   dim3(BB), dim3(256), 0, stream,
                       x, Wi0, bi0, Wi1, bi1, Wi2, bi2);
    hipLaunchKernelGGL(k_scan,  dim3(BB), dim3(512), 0, stream,
                       bv0, bv1, bv2, Wv0, Wv1);
    hipLaunchKernelGGL(k_read,  dim3(BB), dim3(384), 0, stream, Wr, br, out);
}

// Round 22
// 397.052 us; speedup vs baseline: 1.0567x; 1.0567x over previous
//
#include <hip/hip_runtime.h>
#include <math.h>

#define D    6
#define S    128
#define H    128
#define WIN  16
#define BB   8
#define TT   513
#define NW   32
#define OUTD 10

// ---- device-global scratch ----
__device__ float g_lvl1[BB * NW * D];
__device__ float g_area[BB * NW * D * D];
__device__ float g_h0[BB * S];
__device__ float g_hist[BB * (NW + 1) * S];
__device__ float4 g_W2p[3 * 16 * 512];   // packed W2: [ptr][quad i][tid]

__device__ __forceinline__ float sp(float x) {
    return (x > 20.f) ? x : log1pf(expf(x));
}
__device__ __forceinline__ float sigm(float x) {
    return 1.f / (1.f + expf(-x));
}
__device__ __forceinline__ float dot4(float4 a, float4 b, float acc) {
    return fmaf(a.x, b.x, fmaf(a.y, b.y, fmaf(a.z, b.z, fmaf(a.w, b.w, acc))));
}

// ---- LDS layout (float offsets) ----
#define O_W0   0        // [128 r][128 k] fp32 row-major
#define O_W1   16384
#define O_PS   32768    // psum [4 c][6 i][128 r] (3072); aliased psumV [768]
#define O_U    35840    // [6][128] T2
#define O_T    36608    // [6][128] T1
#define O_V    37376    // [768]
#define O_H    38144    // [128] h single buffer
#define O_U1   38400
#define O_U2   38528
#define O_SG1  38656
#define O_SG2  38784
#define O_B0   38912
#define O_B1   39040
#define O_SIG  39168    // [2][44]
#define O_B2   39256    // [768] bv2 staged
#define SMTOT  40024    // 160,096 B

// ---- K0: pack W2 into per-thread coalesced streaming order ----
__global__ __launch_bounds__(512) void k_pack(const float* __restrict__ Wv2) {
    const float4* W24 = (const float4*)Wv2;          // [768][32]
    int e = blockIdx.x * 512 + threadIdx.x;
    if (e < 3 * 16 * 512) {
        int ptr = e >> 13;
        int rem = e & 8191;
        int i   = rem >> 9;
        int tid = rem & 511;
        int r0 = tid >> 1, kh = tid & 1;
        int row = r0 + ptr * 256;
        g_W2p[e] = W24[row * 32 + kh * 16 + i];
    }
}

// ---- K2: windowed log-signature + init MLP ----
__global__ __launch_bounds__(256) void k_sig(
        const float* __restrict__ x,
        const float* __restrict__ Wi0, const float* __restrict__ bi0,
        const float* __restrict__ Wi1, const float* __restrict__ bi1,
        const float* __restrict__ Wi2, const float* __restrict__ bi2) {
    const int b = blockIdx.x;
    const int tid = threadIdx.x;
    __shared__ float dxs[NW][WIN][D];
    __shared__ float cums[NW][WIN][D];
    __shared__ float ua[H], ub[H];

    const float* xb = x + (size_t)b * TT * D;

    if (tid < NW * D) {
        int w = tid / D, i = tid % D;
        float run = 0.f;
        float prev = xb[(w * WIN) * D + i];
        for (int k = 0; k < WIN; ++k) {
            float cur = xb[(w * WIN + k + 1) * D + i];
            float d = cur - prev; prev = cur;
            dxs[w][k][i] = d;
            cums[w][k][i] = run;
            run += d;
        }
        g_lvl1[(b * NW + w) * D + i] = run;
    }
    __syncthreads();
    for (int e = tid; e < NW * D * D; e += blockDim.x) {
        int w = e / (D * D); int rem = e % (D * D);
        int i = rem / D, j = rem % D;
        float s = 0.f;
        for (int k = 0; k < WIN; ++k)
            s += cums[w][k][i] * dxs[w][k][j] - cums[w][k][j] * dxs[w][k][i];
        g_area[(b * NW + w) * (D * D) + rem] = 0.5f * s;
    }
    if (tid < H) {
        float z = bi0[tid];
        for (int k = 0; k < D; ++k) z += Wi0[tid * D + k] * xb[k];
        ua[tid] = sp(z);
    }
    __syncthreads();
    if (tid < H) {
        float z = bi1[tid];
        for (int k = 0; k < H; ++k) z += Wi1[tid * H + k] * ua[k];
        ub[tid] = sp(z);
    }
    __syncthreads();
    if (tid < H) {
        float z = bi2[tid];
        for (int k = 0; k < H; ++k) z += Wi2[tid * H + k] * ub[k];
        g_h0[b * S + tid] = z;
    }
}

// ---- K3: 8 blocks x 512 threads; 11 barrier-phases/step ----
__global__ __launch_bounds__(512, 2) void k_scan(
        const float* __restrict__ bv0, const float* __restrict__ bv1,
        const float* __restrict__ bv2,
        const float* __restrict__ Wv0, const float* __restrict__ Wv1) {
    __shared__ float sm[SMTOT];
    const int tid = threadIdx.x;
    const int b = blockIdx.x;
    const int r   = tid & 127;       // row for W0/W1 psum stages
    const int c4  = tid >> 7;        // k-chunk 0..3 (uniform per wave)
    const int key = r & 7;
    const int kh = tid & 1;
    const int r0 = tid >> 1, r1 = r0 + 256, r2 = r0 + 512;
    const int jA = tid >> 8, jB = 2 + jA, jC = 4 + jA;

    // stage W0, W1, biases
    {
        float4* d = (float4*)(sm + O_W0);
        const float4* s0 = (const float4*)Wv0;
        const float4* s1 = (const float4*)Wv1;
        for (int i = tid; i < 4096; i += 512) { d[i] = s0[i]; d[4096 + i] = s1[i]; }
        sm[O_B2 + tid] = bv2[tid];
        if (tid < 256) sm[O_B2 + 512 + tid] = bv2[512 + tid];
        if (tid < 128) { sm[O_B0 + tid] = bv0[tid]; sm[O_B1 + tid] = bv1[tid]; }
    }
    const float4* WAp = g_W2p + tid;
    const float4* WBp = g_W2p + 8192 + tid;
    const float4* WCp = g_W2p + 16384 + tid;
    if (tid < 128) {
        float h0v = g_h0[b * 128 + tid];
        sm[O_H + tid] = h0v;
        g_hist[(b * (NW + 1)) * 128 + tid] = h0v;
    }
    if (tid >= 448) {
        int q = tid - 448;
        if (q < 42)
            sm[O_SIG + q] = (q < 6) ? g_lvl1[(b * NW) * 6 + q]
                                    : g_area[(b * NW) * 36 + q - 6];
    }
    __syncthreads();

    const float4* W04 = (const float4*)(sm + O_W0);
    const float4* W14 = (const float4*)(sm + O_W1);

    for (int t = 0; t < NW; ++t) {
        float rsig = 0.f;
        if (tid >= 448) {
            int q = tid - 448;
            if (q < 42 && t + 1 < NW)
                rsig = (q < 6) ? g_lvl1[(b * NW + t + 1) * 6 + q]
                               : g_area[(b * NW + t + 1) * 36 + q - 6];
        }
        const int sb = O_SIG + (t & 1) * 44;

        // ---- S1: psum = W0 . h ----
        {
            float a = 0.f;
            const float4* H4 = (const float4*)(sm + O_H);
            #pragma unroll
            for (int q = 0; q < 8; ++q) {
                int qq = c4 * 8 + (q ^ key);
                a = dot4(W04[r * 32 + qq], H4[qq], a);
            }
            sm[O_PS + (c4 * 6) * 128 + r] = a;
        }
        __syncthreads();
        // ---- R1 ----
        if (tid < 128) {
            float z = sm[O_B0 + tid];
            #pragma unroll
            for (int c = 0; c < 4; ++c) z += sm[O_PS + (c * 6) * 128 + tid];
            sm[O_U1 + tid] = sp(z); sm[O_SG1 + tid] = sigm(z);
        }
        __syncthreads();
        // ---- S2: psum = W1 . u1 ----
        {
            float a = 0.f;
            const float4* U14 = (const float4*)(sm + O_U1);
            #pragma unroll
            for (int q = 0; q < 8; ++q) {
                int qq = c4 * 8 + (q ^ key);
                a = dot4(W14[r * 32 + qq], U14[qq], a);
            }
            sm[O_PS + (c4 * 6) * 128 + r] = a;
        }
        __syncthreads();
        // ---- R2 ----
        if (tid < 128) {
            float z = sm[O_B1 + tid];
            #pragma unroll
            for (int c = 0; c < 4; ++c) z += sm[O_PS + (c * 6) * 128 + tid];
            sm[O_U2 + tid] = sp(z); sm[O_SG2 + tid] = sigm(z);
        }
        __syncthreads();
        // ---- S3+R3 merged: V = tanh(b2 + W2.u2)  (packed stream + shfl_xor(1)) ----
        {
            float acc0 = 0.f, acc1 = 0.f, acc2 = 0.f;
            const float4* U24 = (const float4*)(sm + O_U2) + kh * 16;
            #pragma unroll 4
            for (int i = 0; i < 16; ++i) {
                float4 u = U24[i];
                acc0 = dot4(WAp[i * 512], u, acc0);
                acc1 = dot4(WBp[i * 512], u, acc1);
                acc2 = dot4(WCp[i * 512], u, acc2);
            }
            acc0 += __shfl_xor(acc0, 1);
            acc1 += __shfl_xor(acc1, 1);
            acc2 += __shfl_xor(acc2, 1);
            if (kh == 0) {
                sm[O_V + r0]       = tanhf(sm[O_B2 + r0] + acc0);
                sm[O_V + r0 + 256] = tanhf(sm[O_B2 + r0 + 256] + acc1);
            } else {
                sm[O_V + r0 + 512] = tanhf(sm[O_B2 + r0 + 512] + acc2);
            }
        }
        __syncthreads();
        // ---- S4: psum[c][i][r] = W0[r,chunk] . V_i ----
        {
            float a0 = 0.f, a1 = 0.f, a2 = 0.f, a3 = 0.f, a4 = 0.f, a5 = 0.f;
            const float4* V4 = (const float4*)(sm + O_V);
            #pragma unroll
            for (int q = 0; q < 8; ++q) {
                int qq = c4 * 8 + (q ^ key);
                float4 w = W04[r * 32 + qq];
                a0 = dot4(w, V4[qq], a0);
                a1 = dot4(w, V4[32 + qq], a1);
                a2 = dot4(w, V4[64 + qq], a2);
                a3 = dot4(w, V4[96 + qq], a3);
                a4 = dot4(w, V4[128 + qq], a4);
                a5 = dot4(w, V4[160 + qq], a5);
            }
            sm[O_PS + (c4 * 6 + 0) * 128 + r] = a0;
            sm[O_PS + (c4 * 6 + 1) * 128 + r] = a1;
            sm[O_PS + (c4 * 6 + 2) * 128 + r] = a2;
            sm[O_PS + (c4 * 6 + 3) * 128 + r] = a3;
            sm[O_PS + (c4 * 6 + 4) * 128 + r] = a4;
            sm[O_PS + (c4 * 6 + 5) * 128 + r] = a5;
        }
        __syncthreads();
        // ---- R4': per-row y sums once, area fold, T1 (128 threads) ----
        if (tid < 128) {
            float y0 = sm[O_PS + 0 * 128 + tid] + sm[O_PS + 6 * 128 + tid]
                     + sm[O_PS + 12 * 128 + tid] + sm[O_PS + 18 * 128 + tid];
            float y1 = sm[O_PS + 1 * 128 + tid] + sm[O_PS + 7 * 128 + tid]
                     + sm[O_PS + 13 * 128 + tid] + sm[O_PS + 19 * 128 + tid];
            float y2 = sm[O_PS + 2 * 128 + tid] + sm[O_PS + 8 * 128 + tid]
                     + sm[O_PS + 14 * 128 + tid] + sm[O_PS + 20 * 128 + tid];
            float y3 = sm[O_PS + 3 * 128 + tid] + sm[O_PS + 9 * 128 + tid]
                     + sm[O_PS + 15 * 128 + tid] + sm[O_PS + 21 * 128 + tid];
            float y4 = sm[O_PS + 4 * 128 + tid] + sm[O_PS + 10 * 128 + tid]
                     + sm[O_PS + 16 * 128 + tid] + sm[O_PS + 22 * 128 + tid];
            float y5 = sm[O_PS + 5 * 128 + tid] + sm[O_PS + 11 * 128 + tid]
                     + sm[O_PS + 17 * 128 + tid] + sm[O_PS + 23 * 128 + tid];
            float sg = sm[O_SG1 + tid];
            const float* A0 = sm + sb + 6;
            #pragma unroll
            for (int j = 0; j < 6; ++j) {
                float sv = A0[0 * 6 + j] * y0 + A0[1 * 6 + j] * y1
                         + A0[2 * 6 + j] * y2 + A0[3 * 6 + j] * y3
                         + A0[4 * 6 + j] * y4 + A0[5 * 6 + j] * y5;
                sm[O_T + j * 128 + tid] = sg * sv;
            }
        }
        __syncthreads();
        // ---- S5: psum[c][j][r] = W1[r,chunk] . T1_j ----
        {
            float a0 = 0.f, a1 = 0.f, a2 = 0.f, a3 = 0.f, a4 = 0.f, a5 = 0.f;
            const float4* T4 = (const float4*)(sm + O_T);
            #pragma unroll
            for (int q = 0; q < 8; ++q) {
                int qq = c4 * 8 + (q ^ key);
                float4 w = W14[r * 32 + qq];
                a0 = dot4(w, T4[qq], a0);
                a1 = dot4(w, T4[32 + qq], a1);
                a2 = dot4(w, T4[64 + qq], a2);
                a3 = dot4(w, T4[96 + qq], a3);
                a4 = dot4(w, T4[128 + qq], a4);
                a5 = dot4(w, T4[160 + qq], a5);
            }
            sm[O_PS + (c4 * 6 + 0) * 128 + r] = a0;
            sm[O_PS + (c4 * 6 + 1) * 128 + r] = a1;
            sm[O_PS + (c4 * 6 + 2) * 128 + r] = a2;
            sm[O_PS + (c4 * 6 + 3) * 128 + r] = a3;
            sm[O_PS + (c4 * 6 + 4) * 128 + r] = a4;
            sm[O_PS + (c4 * 6 + 5) * 128 + r] = a5;
        }
        __syncthreads();
        // ---- R5: T2_j = sg2 .* sum_c (128 threads) ----
        if (tid < 128) {
            float sg = sm[O_SG2 + tid];
            #pragma unroll
            for (int j = 0; j < 6; ++j) {
                float sv = sm[O_PS + j * 128 + tid] + sm[O_PS + (6 + j) * 128 + tid]
                         + sm[O_PS + (12 + j) * 128 + tid] + sm[O_PS + (18 + j) * 128 + tid];
                sm[O_U + j * 128 + tid] = sg * sv;
            }
        }
        __syncthreads();
        // ---- S6: psumV = W2 . T2_{j(row)} (shfl-merged halves) ----
        {
            float acc0 = 0.f, acc1 = 0.f, acc2 = 0.f;
            const float4* TA = (const float4*)(sm + O_U) + jA * 32 + kh * 16;
            const float4* TB = (const float4*)(sm + O_U) + jB * 32 + kh * 16;
            const float4* TC = (const float4*)(sm + O_U) + jC * 32 + kh * 16;
            #pragma unroll 4
            for (int i = 0; i < 16; ++i) {
                acc0 = dot4(WAp[i * 512], TA[i], acc0);
                acc1 = dot4(WBp[i * 512], TB[i], acc1);
                acc2 = dot4(WCp[i * 512], TC[i], acc2);
            }
            acc0 += __shfl_xor(acc0, 1);
            acc1 += __shfl_xor(acc1, 1);
            acc2 += __shfl_xor(acc2, 1);
            if (kh == 0) {
                sm[O_PS + r0] = acc0;
                sm[O_PS + r0 + 256] = acc1;
            } else {
                sm[O_PS + r0 + 512] = acc2;
            }
        }
        __syncthreads();
        // ---- H: h += l1.V + sum_j (1-V^2)*psV_j; hist; sig store ----
        if (tid < 128) {
            float xh = sm[O_H + tid];
            #pragma unroll
            for (int i = 0; i < 6; ++i)
                xh = fmaf(sm[sb + i], sm[O_V + i * 128 + tid], xh);
            #pragma unroll
            for (int j = 0; j < 6; ++j) {
                float v = sm[O_V + j * 128 + tid];
                xh += (1.f - v * v) * sm[O_PS + j * 128 + tid];
            }
            sm[O_H + tid] = xh;
            g_hist[(b * (NW + 1) + t + 1) * 128 + tid] = xh;
        }
        if (tid >= 448) {
            int q = tid - 448;
            if (q < 42 && t + 1 < NW)
                sm[O_SIG + ((t + 1) & 1) * 44 + q] = rsig;
        }
        __syncthreads();
    }
}

// ---- K4: readout ----
__global__ __launch_bounds__(384) void k_read(const float* __restrict__ Wr,
                                              const float* __restrict__ br,
                                              float* __restrict__ out) {
    const int b = blockIdx.x, e = threadIdx.x;
    if (e < (NW + 1) * OUTD) {
        int t = e / OUTD, o = e % OUTD;
        float z = br[o];
        const float4* hrow = (const float4*)&g_hist[(b * (NW + 1) + t) * 128];
        const float4* wrow = (const float4*)&Wr[o * 128];
        float z0 = 0, z1 = 0, z2 = 0, z3 = 0;
        #pragma unroll 8
        for (int s4 = 0; s4 < 32; ++s4) {
            float4 hv = hrow[s4]; float4 wv = wrow[s4];
            z0 = fmaf(hv.x, wv.x, z0); z1 = fmaf(hv.y, wv.y, z1);
            z2 = fmaf(hv.z, wv.z, z2); z3 = fmaf(hv.w, wv.w, z3);
        }
        out[(b * (NW + 1) + t) * OUTD + o] = z + ((z0 + z1) + (z2 + z3));
    }
}

extern "C" void kernel_launch(void* const* d_in, const int* in_sizes, int n_in,
                              void* d_out, int out_size, void* d_ws, size_t ws_size,
                              hipStream_t stream) {
    const float* x   = (const float*)d_in[0];
    const float* Wi0 = (const float*)d_in[1];
    const float* bi0 = (const float*)d_in[2];
    const float* Wi1 = (const float*)d_in[3];
    const float* bi1 = (const float*)d_in[4];
    const float* Wi2 = (const float*)d_in[5];
    const float* bi2 = (const float*)d_in[6];
    const float* Wv0 = (const float*)d_in[7];
    const float* bv0 = (const float*)d_in[8];
    const float* Wv1 = (const float*)d_in[9];
    const float* bv1 = (const float*)d_in[10];
    const float* Wv2 = (const float*)d_in[11];
    const float* bv2 = (const float*)d_in[12];
    const float* Wr  = (const float*)d_in[13];
    const float* br  = (const float*)d_in[14];
    float* out = (float*)d_out;

    hipLaunchKernelGGL(k_pack, dim3(48), dim3(512), 0, stream, Wv2);
    hipLaunchKernelGGL(k_sig,  dim3(BB), dim3(256), 0, stream,
                       x, Wi0, bi0, Wi1, bi1, Wi2, bi2);
    hipLaunchKernelGGL(k_scan, dim3(BB), dim3(512), 0, stream,
                       bv0, bv1, bv2, Wv0, Wv1);
    hipLaunchKernelGGL(k_read, dim3(BB), dim3(384), 0, stream, Wr, br, out);
}

// Round 23
// 386.945 us; speedup vs baseline: 1.0843x; 1.0261x over previous
//
#include <hip/hip_runtime.h>
#include <math.h>

#define D    6
#define S    128
#define H    128
#define WIN  16
#define BB   8
#define TT   513
#define NW   32
#define OUTD 10

// ---- device-global scratch ----
__device__ float g_lvl1[BB * NW * D];
__device__ float g_area[BB * NW * D * D];
__device__ float g_h0[BB * S];
__device__ float g_hist[BB * (NW + 1) * S];
__device__ float4 g_W2p[3 * 16 * 512];   // packed W2: [ptr][quad i][tid]

__device__ __forceinline__ float sp(float x) {
    return (x > 20.f) ? x : log1pf(expf(x));
}
__device__ __forceinline__ float sigm(float x) {
    return 1.f / (1.f + expf(-x));
}
__device__ __forceinline__ float dot4(float4 a, float4 b, float acc) {
    return fmaf(a.x, b.x, fmaf(a.y, b.y, fmaf(a.z, b.z, fmaf(a.w, b.w, acc))));
}

// ---- LDS layout (float offsets) ----
#define O_W0   0        // [128 r][128 k] fp32 row-major
#define O_W1   16384
#define O_PS   32768    // psum [4 c][6 i][128 r] (3072); aliased psumV [2][768]
#define O_U    35840    // [6][128] T2
#define O_T    36608    // [6][128] T1
#define O_V    37376    // [768]
#define O_H    38144    // [128] h single buffer
#define O_U1   38400
#define O_U2   38528
#define O_SG1  38656
#define O_SG2  38784
#define O_B0   38912
#define O_B1   39040
#define O_SIG  39168    // [2][44]
#define O_B2   39256    // [768] bv2 staged
#define SMTOT  40024    // 160,096 B

// ---- K0: pack W2 into per-thread coalesced streaming order ----
__global__ __launch_bounds__(512) void k_pack(const float* __restrict__ Wv2) {
    const float4* W24 = (const float4*)Wv2;          // [768][32]
    int e = blockIdx.x * 512 + threadIdx.x;
    if (e < 3 * 16 * 512) {
        int ptr = e >> 13;
        int rem = e & 8191;
        int i   = rem >> 9;
        int tid = rem & 511;
        int r0 = tid >> 1, kh = tid & 1;
        int row = r0 + ptr * 256;
        g_W2p[e] = W24[row * 32 + kh * 16 + i];
    }
}

// ---- K2: windowed log-signature + init MLP ----
__global__ __launch_bounds__(256) void k_sig(
        const float* __restrict__ x,
        const float* __restrict__ Wi0, const float* __restrict__ bi0,
        const float* __restrict__ Wi1, const float* __restrict__ bi1,
        const float* __restrict__ Wi2, const float* __restrict__ bi2) {
    const int b = blockIdx.x;
    const int tid = threadIdx.x;
    __shared__ float dxs[NW][WIN][D];
    __shared__ float cums[NW][WIN][D];
    __shared__ float ua[H], ub[H];

    const float* xb = x + (size_t)b * TT * D;

    if (tid < NW * D) {
        int w = tid / D, i = tid % D;
        float run = 0.f;
        float prev = xb[(w * WIN) * D + i];
        for (int k = 0; k < WIN; ++k) {
            float cur = xb[(w * WIN + k + 1) * D + i];
            float d = cur - prev; prev = cur;
            dxs[w][k][i] = d;
            cums[w][k][i] = run;
            run += d;
        }
        g_lvl1[(b * NW + w) * D + i] = run;
    }
    __syncthreads();
    for (int e = tid; e < NW * D * D; e += blockDim.x) {
        int w = e / (D * D); int rem = e % (D * D);
        int i = rem / D, j = rem % D;
        float s = 0.f;
        for (int k = 0; k < WIN; ++k)
            s += cums[w][k][i] * dxs[w][k][j] - cums[w][k][j] * dxs[w][k][i];
        g_area[(b * NW + w) * (D * D) + rem] = 0.5f * s;
    }
    if (tid < H) {
        float z = bi0[tid];
        for (int k = 0; k < D; ++k) z += Wi0[tid * D + k] * xb[k];
        ua[tid] = sp(z);
    }
    __syncthreads();
    if (tid < H) {
        float z = bi1[tid];
        for (int k = 0; k < H; ++k) z += Wi1[tid * H + k] * ua[k];
        ub[tid] = sp(z);
    }
    __syncthreads();
    if (tid < H) {
        float z = bi2[tid];
        for (int k = 0; k < H; ++k) z += Wi2[tid * H + k] * ub[k];
        g_h0[b * S + tid] = z;
    }
}

// ---- K3: 8 blocks x 512 threads; 12 barrier-phases/step; r18 lane mappings ----
__global__ __launch_bounds__(512, 2) void k_scan(
        const float* __restrict__ bv0, const float* __restrict__ bv1,
        const float* __restrict__ bv2,
        const float* __restrict__ Wv0, const float* __restrict__ Wv1) {
    __shared__ float sm[SMTOT];
    const int tid = threadIdx.x;
    const int b = blockIdx.x;
    const int r   = tid & 127;       // row for W0/W1 psum stages (wave-uniform chunk)
    const int c4  = tid >> 7;        // k-chunk 0..3 (uniform per wave)
    const int key = r & 7;
    const int kh = tid & 1;
    const int r0 = tid >> 1, r1 = r0 + 256, r2 = r0 + 512;
    const int jA = tid >> 8, jB = 2 + jA, jC = 4 + jA;

    // stage W0, W1, biases
    {
        float4* d = (float4*)(sm + O_W0);
        const float4* s0 = (const float4*)Wv0;
        const float4* s1 = (const float4*)Wv1;
        for (int i = tid; i < 4096; i += 512) { d[i] = s0[i]; d[4096 + i] = s1[i]; }
        sm[O_B2 + tid] = bv2[tid];
        if (tid < 256) sm[O_B2 + 512 + tid] = bv2[512 + tid];
        if (tid < 128) { sm[O_B0 + tid] = bv0[tid]; sm[O_B1 + tid] = bv1[tid]; }
    }
    const float4* WAp = g_W2p + tid;
    const float4* WBp = g_W2p + 8192 + tid;
    const float4* WCp = g_W2p + 16384 + tid;
    if (tid < 128) {
        float h0v = g_h0[b * 128 + tid];
        sm[O_H + tid] = h0v;
        g_hist[(b * (NW + 1)) * 128 + tid] = h0v;
    }
    if (tid >= 448) {
        int q = tid - 448;
        if (q < 42)
            sm[O_SIG + q] = (q < 6) ? g_lvl1[(b * NW) * 6 + q]
                                    : g_area[(b * NW) * 36 + q - 6];
    }
    __syncthreads();

    const float4* W04 = (const float4*)(sm + O_W0);
    const float4* W14 = (const float4*)(sm + O_W1);

    for (int t = 0; t < NW; ++t) {
        float rsig = 0.f;
        if (tid >= 448) {
            int q = tid - 448;
            if (q < 42 && t + 1 < NW)
                rsig = (q < 6) ? g_lvl1[(b * NW + t + 1) * 6 + q]
                               : g_area[(b * NW + t + 1) * 36 + q - 6];
        }
        const int sb = O_SIG + (t & 1) * 44;

        // ---- S1: psum = W0 . h ----
        {
            float a = 0.f;
            const float4* H4 = (const float4*)(sm + O_H);
            #pragma unroll
            for (int q = 0; q < 8; ++q) {
                int qq = c4 * 8 + (q ^ key);
                a = dot4(W04[r * 32 + qq], H4[qq], a);
            }
            sm[O_PS + (c4 * 6) * 128 + r] = a;
        }
        __syncthreads();
        // ---- R1 ----
        if (tid < 128) {
            float z = sm[O_B0 + tid];
            #pragma unroll
            for (int c = 0; c < 4; ++c) z += sm[O_PS + (c * 6) * 128 + tid];
            sm[O_U1 + tid] = sp(z); sm[O_SG1 + tid] = sigm(z);
        }
        __syncthreads();
        // ---- S2: psum = W1 . u1 ----
        {
            float a = 0.f;
            const float4* U14 = (const float4*)(sm + O_U1);
            #pragma unroll
            for (int q = 0; q < 8; ++q) {
                int qq = c4 * 8 + (q ^ key);
                a = dot4(W14[r * 32 + qq], U14[qq], a);
            }
            sm[O_PS + (c4 * 6) * 128 + r] = a;
        }
        __syncthreads();
        // ---- R2 ----
        if (tid < 128) {
            float z = sm[O_B1 + tid];
            #pragma unroll
            for (int c = 0; c < 4; ++c) z += sm[O_PS + (c * 6) * 128 + tid];
            sm[O_U2 + tid] = sp(z); sm[O_SG2 + tid] = sigm(z);
        }
        __syncthreads();
        // ---- S3: psumV = W2 . u2 (packed coalesced stream) ----
        {
            float acc0 = 0.f, acc1 = 0.f, acc2 = 0.f;
            const float4* U24 = (const float4*)(sm + O_U2) + kh * 16;
            #pragma unroll 4
            for (int i = 0; i < 16; ++i) {
                float4 u = U24[i];
                acc0 = dot4(WAp[i * 512], u, acc0);
                acc1 = dot4(WBp[i * 512], u, acc1);
                acc2 = dot4(WCp[i * 512], u, acc2);
            }
            sm[O_PS + kh * 768 + r0] = acc0;
            sm[O_PS + kh * 768 + r1] = acc1;
            sm[O_PS + kh * 768 + r2] = acc2;
        }
        __syncthreads();
        // ---- R3: V = tanh(b2 + psV0 + psV1) ----
        {
            sm[O_V + tid] = tanhf(sm[O_B2 + tid] + sm[O_PS + tid] + sm[O_PS + 768 + tid]);
            if (tid < 256) {
                int e = tid + 512;
                sm[O_V + e] = tanhf(sm[O_B2 + e] + sm[O_PS + e] + sm[O_PS + 768 + e]);
            }
        }
        __syncthreads();
        // ---- S4: psum[c][i][r] = W0[r,chunk] . V_i ----
        {
            float a0 = 0.f, a1 = 0.f, a2 = 0.f, a3 = 0.f, a4 = 0.f, a5 = 0.f;
            const float4* V4 = (const float4*)(sm + O_V);
            #pragma unroll
            for (int q = 0; q < 8; ++q) {
                int qq = c4 * 8 + (q ^ key);
                float4 w = W04[r * 32 + qq];
                a0 = dot4(w, V4[qq], a0);
                a1 = dot4(w, V4[32 + qq], a1);
                a2 = dot4(w, V4[64 + qq], a2);
                a3 = dot4(w, V4[96 + qq], a3);
                a4 = dot4(w, V4[128 + qq], a4);
                a5 = dot4(w, V4[160 + qq], a5);
            }
            sm[O_PS + (c4 * 6 + 0) * 128 + r] = a0;
            sm[O_PS + (c4 * 6 + 1) * 128 + r] = a1;
            sm[O_PS + (c4 * 6 + 2) * 128 + r] = a2;
            sm[O_PS + (c4 * 6 + 3) * 128 + r] = a3;
            sm[O_PS + (c4 * 6 + 4) * 128 + r] = a4;
            sm[O_PS + (c4 * 6 + 5) * 128 + r] = a5;
        }
        __syncthreads();
        // ---- R4': per-row y sums once, area fold, T1 ----
        {
            #pragma unroll
            for (int s = 0; s < 2; ++s) {
                int e = tid + s * 512;
                if (s == 0 || tid < 256) {
                    int jj = e >> 7, rr = e & 127;
                    float y0 = sm[O_PS + 0 * 128 + rr] + sm[O_PS + (6 + 0) * 128 + rr]
                             + sm[O_PS + (12 + 0) * 128 + rr] + sm[O_PS + (18 + 0) * 128 + rr];
                    float y1 = sm[O_PS + 1 * 128 + rr] + sm[O_PS + (6 + 1) * 128 + rr]
                             + sm[O_PS + (12 + 1) * 128 + rr] + sm[O_PS + (18 + 1) * 128 + rr];
                    float y2 = sm[O_PS + 2 * 128 + rr] + sm[O_PS + (6 + 2) * 128 + rr]
                             + sm[O_PS + (12 + 2) * 128 + rr] + sm[O_PS + (18 + 2) * 128 + rr];
                    float y3 = sm[O_PS + 3 * 128 + rr] + sm[O_PS + (6 + 3) * 128 + rr]
                             + sm[O_PS + (12 + 3) * 128 + rr] + sm[O_PS + (18 + 3) * 128 + rr];
                    float y4 = sm[O_PS + 4 * 128 + rr] + sm[O_PS + (6 + 4) * 128 + rr]
                             + sm[O_PS + (12 + 4) * 128 + rr] + sm[O_PS + (18 + 4) * 128 + rr];
                    float y5 = sm[O_PS + 5 * 128 + rr] + sm[O_PS + (6 + 5) * 128 + rr]
                             + sm[O_PS + (12 + 5) * 128 + rr] + sm[O_PS + (18 + 5) * 128 + rr];
                    const float* A0 = sm + sb + 6;
                    float sv = A0[0 * 6 + jj] * y0 + A0[1 * 6 + jj] * y1
                             + A0[2 * 6 + jj] * y2 + A0[3 * 6 + jj] * y3
                             + A0[4 * 6 + jj] * y4 + A0[5 * 6 + jj] * y5;
                    sm[O_T + jj * 128 + rr] = sm[O_SG1 + rr] * sv;
                }
            }
        }
        __syncthreads();
        // ---- S5: psum[c][j][r] = W1[r,chunk] . T1_j ----
        {
            float a0 = 0.f, a1 = 0.f, a2 = 0.f, a3 = 0.f, a4 = 0.f, a5 = 0.f;
            const float4* T4 = (const float4*)(sm + O_T);
            #pragma unroll
            for (int q = 0; q < 8; ++q) {
                int qq = c4 * 8 + (q ^ key);
                float4 w = W14[r * 32 + qq];
                a0 = dot4(w, T4[qq], a0);
                a1 = dot4(w, T4[32 + qq], a1);
                a2 = dot4(w, T4[64 + qq], a2);
                a3 = dot4(w, T4[96 + qq], a3);
                a4 = dot4(w, T4[128 + qq], a4);
                a5 = dot4(w, T4[160 + qq], a5);
            }
            sm[O_PS + (c4 * 6 + 0) * 128 + r] = a0;
            sm[O_PS + (c4 * 6 + 1) * 128 + r] = a1;
            sm[O_PS + (c4 * 6 + 2) * 128 + r] = a2;
            sm[O_PS + (c4 * 6 + 3) * 128 + r] = a3;
            sm[O_PS + (c4 * 6 + 4) * 128 + r] = a4;
            sm[O_PS + (c4 * 6 + 5) * 128 + r] = a5;
        }
        __syncthreads();
        // ---- R5: T2_j = sg2 .* sum_c ----
        {
            #pragma unroll
            for (int s = 0; s < 2; ++s) {
                int e = tid + s * 512;
                if (s == 0 || tid < 256) {
                    int jj = e >> 7, rr = e & 127;
                    float sv = sm[O_PS + jj * 128 + rr] + sm[O_PS + (6 + jj) * 128 + rr]
                             + sm[O_PS + (12 + jj) * 128 + rr] + sm[O_PS + (18 + jj) * 128 + rr];
                    sm[O_U + jj * 128 + rr] = sm[O_SG2 + rr] * sv;
                }
            }
        }
        __syncthreads();
        // ---- S6: psumV = W2 . T2_{j(row)} ----
        {
            float acc0 = 0.f, acc1 = 0.f, acc2 = 0.f;
            const float4* TA = (const float4*)(sm + O_U) + jA * 32 + kh * 16;
            const float4* TB = (const float4*)(sm + O_U) + jB * 32 + kh * 16;
            const float4* TC = (const float4*)(sm + O_U) + jC * 32 + kh * 16;
            #pragma unroll 4
            for (int i = 0; i < 16; ++i) {
                acc0 = dot4(WAp[i * 512], TA[i], acc0);
                acc1 = dot4(WBp[i * 512], TB[i], acc1);
                acc2 = dot4(WCp[i * 512], TC[i], acc2);
            }
            sm[O_PS + kh * 768 + r0] = acc0;
            sm[O_PS + kh * 768 + r1] = acc1;
            sm[O_PS + kh * 768 + r2] = acc2;
        }
        __syncthreads();
        // ---- H (merged R6): h += l1.V + sum_j (1-V^2)(psV0+psV1); hist; sig store ----
        if (tid < 128) {
            float xh = sm[O_H + tid];
            #pragma unroll
            for (int i = 0; i < 6; ++i)
                xh = fmaf(sm[sb + i], sm[O_V + i * 128 + tid], xh);
            #pragma unroll
            for (int j = 0; j < 6; ++j) {
                float v = sm[O_V + j * 128 + tid];
                xh += (1.f - v * v) * (sm[O_PS + j * 128 + tid] + sm[O_PS + 768 + j * 128 + tid]);
            }
            sm[O_H + tid] = xh;
            g_hist[(b * (NW + 1) + t + 1) * 128 + tid] = xh;
        }
        if (tid >= 448) {
            int q = tid - 448;
            if (q < 42 && t + 1 < NW)
                sm[O_SIG + ((t + 1) & 1) * 44 + q] = rsig;
        }
        __syncthreads();
    }
}

// ---- K4: readout ----
__global__ __launch_bounds__(384) void k_read(const float* __restrict__ Wr,
                                              const float* __restrict__ br,
                                              float* __restrict__ out) {
    const int b = blockIdx.x, e = threadIdx.x;
    if (e < (NW + 1) * OUTD) {
        int t = e / OUTD, o = e % OUTD;
        float z = br[o];
        const float4* hrow = (const float4*)&g_hist[(b * (NW + 1) + t) * 128];
        const float4* wrow = (const float4*)&Wr[o * 128];
        float z0 = 0, z1 = 0, z2 = 0, z3 = 0;
        #pragma unroll 8
        for (int s4 = 0; s4 < 32; ++s4) {
            float4 hv = hrow[s4]; float4 wv = wrow[s4];
            z0 = fmaf(hv.x, wv.x, z0); z1 = fmaf(hv.y, wv.y, z1);
            z2 = fmaf(hv.z, wv.z, z2); z3 = fmaf(hv.w, wv.w, z3);
        }
        out[(b * (NW + 1) + t) * OUTD + o] = z + ((z0 + z1) + (z2 + z3));
    }
}

extern "C" void kernel_launch(void* const* d_in, const int* in_sizes, int n_in,
                              void* d_out, int out_size, void* d_ws, size_t ws_size,
                              hipStream_t stream) {
    const float* x   = (const float*)d_in[0];
    const float* Wi0 = (const float*)d_in[1];
    const float* bi0 = (const float*)d_in[2];
    const float* Wi1 = (const float*)d_in[3];
    const float* bi1 = (const float*)d_in[4];
    const float* Wi2 = (const float*)d_in[5];
    const float* bi2 = (const float*)d_in[6];
    const float* Wv0 = (const float*)d_in[7];
    const float* bv0 = (const float*)d_in[8];
    const float* Wv1 = (const float*)d_in[9];
    const float* bv1 = (const float*)d_in[10];
    const float* Wv2 = (const float*)d_in[11];
    const float* bv2 = (const float*)d_in[12];
    const float* Wr  = (const float*)d_in[13];
    const float* br  = (const float*)d_in[14];
    float* out = (float*)d_out;

    hipLaunchKernelGGL(k_pack, dim3(48), dim3(512), 0, stream, Wv2);
    hipLaunchKernelGGL(k_sig,  dim3(BB), dim3(256), 0, stream,
                       x, Wi0, bi0, Wi1, bi1, Wi2, bi2);
    hipLaunchKernelGGL(k_scan, dim3(BB), dim3(512), 0, stream,
                       bv0, bv1, bv2, Wv0, Wv1);
    hipLaunchKernelGGL(k_read, dim3(BB), dim3(384), 0, stream, Wr, br, out);
}